// Round 24
// baseline (65.579 us; speedup 1.0000x reference)
//
#include <hip/hip_runtime.h>
#include <hip/hip_fp16.h>

#define KDIM 1024
#define DDIM 64
#define SPAT 32768
#define NVEC 65536
#define DSP  (DDIM * SPAT)          // 2097152
#define MARGIN 3.0e-4f              // 1.5x worst-case bound 2e-4 (fp16 e/z rounding at max-norm row)
#define ZPAD 69
#define QCAP 1536
#define BLK  512                    // 8 waves: within-block k-split, 8 t-steps/wave/pass

typedef _Float16 half8 __attribute__((ext_vector_type(8)));
typedef float floatx4 __attribute__((ext_vector_type(4)));

__device__ __forceinline__ float opaque(float x) { asm volatile("" : "+v"(x)); return x; }

// Bitwise replica of np.add.reduce pairwise base case over fl(x[d]^2), d=0..63 (R3-proven)
__device__ __forceinline__ float np_sumsq64(const float* x) {
    float r8[8];
#pragma unroll
    for (int j = 0; j < 8; ++j) r8[j] = opaque(x[1 + j] * x[1 + j]);
#pragma unroll
    for (int i = 8; i < 56; i += 8) {
#pragma unroll
        for (int j = 0; j < 8; ++j) r8[j] += opaque(x[1 + i + j] * x[1 + i + j]);
    }
    float res = ((r8[0] + r8[1]) + (r8[2] + r8[3])) + ((r8[4] + r8[5]) + (r8[6] + r8[7]));
#pragma unroll
    for (int m = 57; m < 64; ++m) res += opaque(x[m] * x[m]);
    return opaque(x[0] * x[0]) + res;
}

// K1 (64 blocks x 16 k-rows, coalesced): h = np-f32 ||e||^2, e2 = 2e, eh = fp16(e*1024); loss=0
__global__ void vq_prep_e(const float* __restrict__ emb, float* __restrict__ e2,
                          float* __restrict__ h, __half* __restrict__ eh,
                          float* __restrict__ loss) {
    const int tid = threadIdx.x;
    const int kbase = blockIdx.x * 16;
#pragma unroll
    for (int i = 0; i < 4; ++i) {
        int g = i * 256 + tid;
        float v = emb[(size_t)kbase * DDIM + g];
        e2[(size_t)kbase * DDIM + g] = v + v;
        eh[(size_t)kbase * DDIM + g] = (__half)(_Float16)(v * 1024.0f);
    }
    if (tid < 16) h[kbase + tid] = np_sumsq64(emb + (size_t)(kbase + tid) * DDIM);
    if (blockIdx.x == 0 && tid == 0) *loss = 0.f;
}

// K2: R22 logic at BLK=512 (8 waves, within-block k-split): 2x waves/SIMD for latency hiding.
__global__ __launch_bounds__(BLK, 4) void vq_mfma_kernel(
    const float* __restrict__ z, const float* __restrict__ emb,
    const __half* __restrict__ eh_, const float* __restrict__ h_,
    const float* __restrict__ e2_, float* __restrict__ out,
    float* __restrict__ loss, float* __restrict__ idxf)
{
    __shared__ float zrow[64 * ZPAD];     // 17.7 KB
    __shared__ float lds_sn[64];
    __shared__ float Lm1[32][64];         // 8 KB (8 waves x 4 g16-groups)
    __shared__ float m1f[64];
    __shared__ int   qcnt;
    __shared__ unsigned short      qk[QCAP];   // 3 KB
    __shared__ unsigned char       qn[QCAP];   // 1.5 KB
    __shared__ unsigned long long  rbest[64];  // 0.5 KB

    const int tid = threadIdx.x, l = tid & 63, w = tid >> 6;   // w in 0..7
    const int nbase = blockIdx.x * 64;
    const int b = nbase >> 15, s0 = nbase & (SPAT - 1);
    const int col16 = l & 15, g16 = l >> 4;
    const float* zbase = z + (size_t)b * DSP + s0;

    if (tid == 0) qcnt = 0;
    if (tid < 64) rbest[tid] = ~0ull;

    // stage 64 z-rows (coalesced 256B groups, 8 iters x 512 threads)
#pragma unroll
    for (int j = 0; j < 8; ++j) {
        const int g = j * BLK + tid;
        const int d = g >> 6, r = g & 63;
        zrow[r * ZPAD + d] = zbase[(size_t)d * SPAT + r];
    }
    __syncthreads();

    if (tid < 64) lds_sn[tid] = np_sumsq64(&zrow[tid * ZPAD]);

    // resident Z hi fragments: zf[nc][kp] (identical per wave)
    half8 zf[4][2];
#pragma unroll
    for (int nc = 0; nc < 4; ++nc) {
        const int r = nc * 16 + col16;
#pragma unroll
        for (int kp = 0; kp < 2; ++kp) {
            const int d0 = g16 * 8 + kp * 32;
            half8 vh;
#pragma unroll
            for (int u = 0; u < 8; ++u)
                vh[u] = (_Float16)zrow[r * ZPAD + d0 + u];
            zf[nc][kp] = vh;
        }
    }
    __syncthreads();

    float snv[4];
#pragma unroll
    for (int nc = 0; nc < 4; ++nc) snv[nc] = lds_sn[nc * 16 + col16];

    const int myk0 = w * 128;             // wave's 128-k range, 8 t-steps

    // ---- phase 1: approx min per column (hi-only, prefetched) ----
    float m1[4];
#pragma unroll
    for (int nc = 0; nc < 4; ++nc) m1[nc] = 3.0e38f;
    {
        size_t eoff = (size_t)(myk0 + col16) * DDIM + g16 * 8;
        half8 ef0 = *(const half8*)(eh_ + eoff);
        half8 ef1 = *(const half8*)(eh_ + eoff + 32);
        floatx4 hv = *(const floatx4*)(h_ + myk0 + g16 * 4);
        for (int t = 0; t < 8; ++t) {
            half8 cf0 = ef0, cf1 = ef1; floatx4 chv = hv;
            if (t < 7) {
                const size_t e2off = (size_t)(myk0 + (t + 1) * 16 + col16) * DDIM + g16 * 8;
                ef0 = *(const half8*)(eh_ + e2off);
                ef1 = *(const half8*)(eh_ + e2off + 32);
                hv  = *(const floatx4*)(h_ + myk0 + (t + 1) * 16 + g16 * 4);
            }
#pragma unroll
            for (int nc = 0; nc < 4; ++nc) {
                floatx4 acc = {0.f, 0.f, 0.f, 0.f};
                acc = __builtin_amdgcn_mfma_f32_16x16x32_f16(cf0, zf[nc][0], acc, 0, 0, 0);
                acc = __builtin_amdgcn_mfma_f32_16x16x32_f16(cf1, zf[nc][1], acc, 0, 0, 0);
#pragma unroll
                for (int j = 0; j < 4; ++j) {
                    float dist = fmaf(-0.001953125f, acc[j], snv[nc] + chv[j]);
                    m1[nc] = fminf(m1[nc], dist);
                }
            }
        }
    }
    const int slot = w * 4 + g16;
#pragma unroll
    for (int nc = 0; nc < 4; ++nc) Lm1[slot][nc * 16 + col16] = m1[nc];
    __syncthreads();

    if (tid < 64) {
        float M1 = Lm1[0][tid];
#pragma unroll
        for (int sI = 1; sI < 32; ++sI) M1 = fminf(M1, Lm1[sI][tid]);
        m1f[tid] = M1;
    }
    __syncthreads();

    // ---- phase 2: re-scan, push candidates within MARGIN of min ----
    float thr[4];
#pragma unroll
    for (int nc = 0; nc < 4; ++nc) thr[nc] = m1f[nc * 16 + col16] + MARGIN;
    {
        size_t eoff = (size_t)(myk0 + col16) * DDIM + g16 * 8;
        half8 ef0 = *(const half8*)(eh_ + eoff);
        half8 ef1 = *(const half8*)(eh_ + eoff + 32);
        floatx4 hv = *(const floatx4*)(h_ + myk0 + g16 * 4);
        for (int t = 0; t < 8; ++t) {
            half8 cf0 = ef0, cf1 = ef1; floatx4 chv = hv;
            if (t < 7) {
                const size_t e2off = (size_t)(myk0 + (t + 1) * 16 + col16) * DDIM + g16 * 8;
                ef0 = *(const half8*)(eh_ + e2off);
                ef1 = *(const half8*)(eh_ + e2off + 32);
                hv  = *(const floatx4*)(h_ + myk0 + (t + 1) * 16 + g16 * 4);
            }
            const int rbase = myk0 + t * 16 + g16 * 4;
#pragma unroll
            for (int nc = 0; nc < 4; ++nc) {
                floatx4 acc = {0.f, 0.f, 0.f, 0.f};
                acc = __builtin_amdgcn_mfma_f32_16x16x32_f16(cf0, zf[nc][0], acc, 0, 0, 0);
                acc = __builtin_amdgcn_mfma_f32_16x16x32_f16(cf1, zf[nc][1], acc, 0, 0, 0);
#pragma unroll
                for (int j = 0; j < 4; ++j) {
                    float dist = fmaf(-0.001953125f, acc[j], snv[nc] + chv[j]);
                    if (dist <= thr[nc]) {
                        int p = atomicAdd(&qcnt, 1);
                        if (p < QCAP) {
                            qk[p] = (unsigned short)(rbase + j);
                            qn[p] = (unsigned char)(nc * 16 + col16);
                        }
                    }
                }
            }
        }
    }
    __syncthreads();

    const int qlen = min(qcnt, QCAP);

    // ---- phase 3: bit-exact numpy-f32 rescore, fused per-row atomicMin ----
    for (int i = tid; i < qlen; i += BLK) {
        const int k = qk[i], r = qn[i];
        const float* zr = &zrow[r * ZPAD];
        const floatx4* ep = (const floatx4*)(e2_ + (size_t)k * DDIM);
        float acc = 0.f;
#pragma unroll
        for (int dq = 0; dq < 16; ++dq) {
            floatx4 v = ep[dq];
            acc = fmaf(v[0], zr[4 * dq + 0], acc);   // sequential ascending d from 0
            acc = fmaf(v[1], zr[4 * dq + 1], acc);
            acc = fmaf(v[2], zr[4 * dq + 2], acc);
            acc = fmaf(v[3], zr[4 * dq + 3], acc);
        }
        float tt   = lds_sn[r] + h_[k];   // fl(sn + h)
        float dist = tt - acc;            // fl(t - 2 z.e)
        unsigned int db = __float_as_uint(dist);   // dist > 0 -> monotonic bits
        atomicMin(&rbest[r], ((unsigned long long)db << 32) | (unsigned int)k);
    }
    __syncthreads();

    if (qcnt > QCAP) {   // cold correctness fallback: full exact scan (never in practice)
        const int row = tid & 63, kq = tid >> 6;     // kq in 0..7
        for (int k = kq * 128; k < kq * 128 + 128; ++k) {
            const float* zr = &zrow[row * ZPAD];
            const floatx4* ep = (const floatx4*)(e2_ + (size_t)k * DDIM);
            float acc = 0.f;
#pragma unroll
            for (int dq = 0; dq < 16; ++dq) {
                floatx4 v = ep[dq];
                acc = fmaf(v[0], zr[4 * dq + 0], acc);
                acc = fmaf(v[1], zr[4 * dq + 1], acc);
                acc = fmaf(v[2], zr[4 * dq + 2], acc);
                acc = fmaf(v[3], zr[4 * dq + 3], acc);
            }
            float tt   = lds_sn[row] + h_[k];
            float dist = tt - acc;
            atomicMin(&rbest[row],
                      ((unsigned long long)__float_as_uint(dist) << 32) | (unsigned int)k);
        }
        __syncthreads();
    }

    // ---- phase 4: epilogue (idx, z_q gather, loss) ----
    if (tid < 64) {
        const int I1 = (int)(rbest[tid] & 0xffffffffu);
        const int n = nbase + tid;
        idxf[n] = (float)I1;

        const float* e = emb + (size_t)I1 * DDIM;
        float* op = out + (size_t)b * DSP + s0 + tid;
        float lsum = 0.f;
#pragma unroll
        for (int d = 0; d < DDIM; ++d) {
            float qv = e[d];
            op[(size_t)d * SPAT] = qv;
            float df = qv - zrow[tid * ZPAD + d];
            lsum = fmaf(df, df, lsum);
        }
#pragma unroll
        for (int off = 32; off > 0; off >>= 1)
            lsum += __shfl_down(lsum, off, 64);
        if (tid == 0)
            atomicAdd(loss, lsum * (1.25f / 4194304.0f));
    }
}

extern "C" void kernel_launch(void* const* d_in, const int* in_sizes, int n_in,
                              void* d_out, int out_size, void* d_ws, size_t ws_size,
                              hipStream_t stream) {
    const float* z   = (const float*)d_in[0];   // [2, 64, 32, 32, 32]
    const float* emb = (const float*)d_in[1];   // [1024, 64]
    float* out  = (float*)d_out;                // z_q (4194304) | loss (1) | indices (65536)
    float* loss = out + 4194304;
    float* idxf = out + 4194305;

    float* h_  = (float*)d_ws;                  // [1024]
    float* e2_ = h_ + KDIM;                     // [1024*64]
    __half* eh_ = (__half*)(e2_ + KDIM * DDIM); // [1024*64] halves

    vq_prep_e<<<KDIM / 16, 256, 0, stream>>>(emb, e2_, h_, eh_, loss);
    vq_mfma_kernel<<<NVEC / 64, BLK, 0, stream>>>(z, emb, eh_, h_, e2_, out, loss, idxf);
}

// Round 25
// 62.714 us; speedup vs baseline: 1.0457x; 1.0457x over previous
//
#include <hip/hip_runtime.h>
#include <hip/hip_fp16.h>

#define KDIM 1024
#define DDIM 64
#define SPAT 32768
#define NVEC 65536
#define DSP  (DDIM * SPAT)          // 2097152
#define MARGIN 3.0e-4f              // 1.5x worst-case bound 2e-4 (fp16 e/z rounding at max-norm row)
#define ZPAD 69
#define QCAP 1536

typedef _Float16 half8 __attribute__((ext_vector_type(8)));
typedef float floatx4 __attribute__((ext_vector_type(4)));

__device__ __forceinline__ float opaque(float x) { asm volatile("" : "+v"(x)); return x; }

// Bitwise replica of np.add.reduce pairwise base case over fl(x[d]^2), d=0..63 (R3-proven)
__device__ __forceinline__ float np_sumsq64(const float* x) {
    float r8[8];
#pragma unroll
    for (int j = 0; j < 8; ++j) r8[j] = opaque(x[1 + j] * x[1 + j]);
#pragma unroll
    for (int i = 8; i < 56; i += 8) {
#pragma unroll
        for (int j = 0; j < 8; ++j) r8[j] += opaque(x[1 + i + j] * x[1 + i + j]);
    }
    float res = ((r8[0] + r8[1]) + (r8[2] + r8[3])) + ((r8[4] + r8[5]) + (r8[6] + r8[7]));
#pragma unroll
    for (int m = 57; m < 64; ++m) res += opaque(x[m] * x[m]);
    return opaque(x[0] * x[0]) + res;
}

// K1 (64 blocks x 16 k-rows, coalesced): h = np-f32 ||e||^2, e2 = 2e, eh = fp16(e*1024); loss=0
__global__ void vq_prep_e(const float* __restrict__ emb, float* __restrict__ e2,
                          float* __restrict__ h, __half* __restrict__ eh,
                          float* __restrict__ loss) {
    const int tid = threadIdx.x;
    const int kbase = blockIdx.x * 16;
#pragma unroll
    for (int i = 0; i < 4; ++i) {
        int g = i * 256 + tid;
        float v = emb[(size_t)kbase * DDIM + g];
        e2[(size_t)kbase * DDIM + g] = v + v;
        eh[(size_t)kbase * DDIM + g] = (__half)(_Float16)(v * 1024.0f);
    }
    if (tid < 16) h[kbase + tid] = np_sumsq64(emb + (size_t)(kbase + tid) * DDIM);
    if (blockIdx.x == 0 && tid == 0) *loss = 0.f;
}

// K2: R18-verbatim scan phases; phase 3 fused with per-row atomicMin (no qres/phase-4 scan).
__global__ __launch_bounds__(256, 4) void vq_mfma_kernel(
    const float* __restrict__ z, const float* __restrict__ emb,
    const __half* __restrict__ eh_, const float* __restrict__ h_,
    const float* __restrict__ e2_, float* __restrict__ out,
    float* __restrict__ loss, float* __restrict__ idxf)
{
    __shared__ float zrow[64 * ZPAD];     // 17.7 KB
    __shared__ float lds_sn[64];
    __shared__ float Lm1[16][64];         // 4 KB
    __shared__ float m1f[64];
    __shared__ int   qcnt;
    __shared__ unsigned short      qk[QCAP];   // 3 KB
    __shared__ unsigned char       qn[QCAP];   // 1.5 KB
    __shared__ unsigned long long  rbest[64];  // 0.5 KB

    const int tid = threadIdx.x, l = tid & 63, w = tid >> 6;
    const int nbase = blockIdx.x * 64;
    const int b = nbase >> 15, s0 = nbase & (SPAT - 1);
    const int col16 = l & 15, g16 = l >> 4;
    const float* zbase = z + (size_t)b * DSP + s0;

    if (tid == 0) qcnt = 0;
    if (tid < 64) rbest[tid] = ~0ull;

    // stage 64 z-rows: wave w loads d in [w*16, w*16+16), lane = row (coalesced 256B)
    {
        const int dbase = w * 16;
#pragma unroll
        for (int j = 0; j < 16; ++j)
            zrow[l * ZPAD + dbase + j] = zbase[(size_t)(dbase + j) * SPAT + l];
    }
    __syncthreads();

    if (tid < 64) lds_sn[tid] = np_sumsq64(&zrow[tid * ZPAD]);

    // resident Z hi fragments: zf[nc][kp]
    half8 zf[4][2];
#pragma unroll
    for (int nc = 0; nc < 4; ++nc) {
        const int r = nc * 16 + col16;
#pragma unroll
        for (int kp = 0; kp < 2; ++kp) {
            const int d0 = g16 * 8 + kp * 32;
            half8 vh;
#pragma unroll
            for (int u = 0; u < 8; ++u)
                vh[u] = (_Float16)zrow[r * ZPAD + d0 + u];
            zf[nc][kp] = vh;
        }
    }
    __syncthreads();

    float snv[4];
#pragma unroll
    for (int nc = 0; nc < 4; ++nc) snv[nc] = lds_sn[nc * 16 + col16];

    const int myk0 = w * 256;

    // ---- phase 1: approx min per column (hi-only, prefetched) ----
    float m1[4];
#pragma unroll
    for (int nc = 0; nc < 4; ++nc) m1[nc] = 3.0e38f;
    {
        size_t eoff = (size_t)(myk0 + col16) * DDIM + g16 * 8;
        half8 ef0 = *(const half8*)(eh_ + eoff);
        half8 ef1 = *(const half8*)(eh_ + eoff + 32);
        floatx4 hv = *(const floatx4*)(h_ + myk0 + g16 * 4);
        for (int t = 0; t < 16; ++t) {
            half8 cf0 = ef0, cf1 = ef1; floatx4 chv = hv;
            if (t < 15) {
                const size_t e2off = (size_t)(myk0 + (t + 1) * 16 + col16) * DDIM + g16 * 8;
                ef0 = *(const half8*)(eh_ + e2off);
                ef1 = *(const half8*)(eh_ + e2off + 32);
                hv  = *(const floatx4*)(h_ + myk0 + (t + 1) * 16 + g16 * 4);
            }
#pragma unroll
            for (int nc = 0; nc < 4; ++nc) {
                floatx4 acc = {0.f, 0.f, 0.f, 0.f};
                acc = __builtin_amdgcn_mfma_f32_16x16x32_f16(cf0, zf[nc][0], acc, 0, 0, 0);
                acc = __builtin_amdgcn_mfma_f32_16x16x32_f16(cf1, zf[nc][1], acc, 0, 0, 0);
#pragma unroll
                for (int j = 0; j < 4; ++j) {
                    float dist = fmaf(-0.001953125f, acc[j], snv[nc] + chv[j]);
                    m1[nc] = fminf(m1[nc], dist);
                }
            }
        }
    }
    const int slot = w * 4 + g16;
#pragma unroll
    for (int nc = 0; nc < 4; ++nc) Lm1[slot][nc * 16 + col16] = m1[nc];
    __syncthreads();

    if (tid < 64) {
        float M1 = Lm1[0][tid];
#pragma unroll
        for (int sI = 1; sI < 16; ++sI) M1 = fminf(M1, Lm1[sI][tid]);
        m1f[tid] = M1;
    }
    __syncthreads();

    // ---- phase 2: re-scan, push candidates within MARGIN of min ----
    float thr[4];
#pragma unroll
    for (int nc = 0; nc < 4; ++nc) thr[nc] = m1f[nc * 16 + col16] + MARGIN;
    {
        size_t eoff = (size_t)(myk0 + col16) * DDIM + g16 * 8;
        half8 ef0 = *(const half8*)(eh_ + eoff);
        half8 ef1 = *(const half8*)(eh_ + eoff + 32);
        floatx4 hv = *(const floatx4*)(h_ + myk0 + g16 * 4);
        for (int t = 0; t < 16; ++t) {
            half8 cf0 = ef0, cf1 = ef1; floatx4 chv = hv;
            if (t < 15) {
                const size_t e2off = (size_t)(myk0 + (t + 1) * 16 + col16) * DDIM + g16 * 8;
                ef0 = *(const half8*)(eh_ + e2off);
                ef1 = *(const half8*)(eh_ + e2off + 32);
                hv  = *(const floatx4*)(h_ + myk0 + (t + 1) * 16 + g16 * 4);
            }
            const int rbase = myk0 + t * 16 + g16 * 4;
#pragma unroll
            for (int nc = 0; nc < 4; ++nc) {
                floatx4 acc = {0.f, 0.f, 0.f, 0.f};
                acc = __builtin_amdgcn_mfma_f32_16x16x32_f16(cf0, zf[nc][0], acc, 0, 0, 0);
                acc = __builtin_amdgcn_mfma_f32_16x16x32_f16(cf1, zf[nc][1], acc, 0, 0, 0);
#pragma unroll
                for (int j = 0; j < 4; ++j) {
                    float dist = fmaf(-0.001953125f, acc[j], snv[nc] + chv[j]);
                    if (dist <= thr[nc]) {
                        int p = atomicAdd(&qcnt, 1);
                        if (p < QCAP) {
                            qk[p] = (unsigned short)(rbase + j);
                            qn[p] = (unsigned char)(nc * 16 + col16);
                        }
                    }
                }
            }
        }
    }
    __syncthreads();

    const int qlen = min(qcnt, QCAP);

    // ---- phase 3: bit-exact numpy-f32 rescore, fused per-row atomicMin ----
    for (int i = tid; i < qlen; i += 256) {
        const int k = qk[i], r = qn[i];
        const float* zr = &zrow[r * ZPAD];
        const floatx4* ep = (const floatx4*)(e2_ + (size_t)k * DDIM);
        float acc = 0.f;
#pragma unroll
        for (int dq = 0; dq < 16; ++dq) {
            floatx4 v = ep[dq];
            acc = fmaf(v[0], zr[4 * dq + 0], acc);   // sequential ascending d from 0
            acc = fmaf(v[1], zr[4 * dq + 1], acc);
            acc = fmaf(v[2], zr[4 * dq + 2], acc);
            acc = fmaf(v[3], zr[4 * dq + 3], acc);
        }
        float tt   = lds_sn[r] + h_[k];   // fl(sn + h)
        float dist = tt - acc;            // fl(t - 2 z.e)
        unsigned int db = __float_as_uint(dist);   // dist > 0 -> monotonic bits
        atomicMin(&rbest[r], ((unsigned long long)db << 32) | (unsigned int)k);
    }
    __syncthreads();

    if (qcnt > QCAP) {   // cold correctness fallback: full exact scan (never in practice)
        const int row = tid & 63, kq = tid >> 6;
        for (int k = kq * 256; k < kq * 256 + 256; ++k) {
            const float* zr = &zrow[row * ZPAD];
            const floatx4* ep = (const floatx4*)(e2_ + (size_t)k * DDIM);
            float acc = 0.f;
#pragma unroll
            for (int dq = 0; dq < 16; ++dq) {
                floatx4 v = ep[dq];
                acc = fmaf(v[0], zr[4 * dq + 0], acc);
                acc = fmaf(v[1], zr[4 * dq + 1], acc);
                acc = fmaf(v[2], zr[4 * dq + 2], acc);
                acc = fmaf(v[3], zr[4 * dq + 3], acc);
            }
            float tt   = lds_sn[row] + h_[k];
            float dist = tt - acc;
            atomicMin(&rbest[row],
                      ((unsigned long long)__float_as_uint(dist) << 32) | (unsigned int)k);
        }
        __syncthreads();
    }

    // ---- phase 4: epilogue (idx, z_q gather, loss) ----
    if (tid < 64) {
        const int I1 = (int)(rbest[tid] & 0xffffffffu);
        const int n = nbase + tid;
        idxf[n] = (float)I1;

        const float* e = emb + (size_t)I1 * DDIM;
        float* op = out + (size_t)b * DSP + s0 + tid;
        float lsum = 0.f;
#pragma unroll
        for (int d = 0; d < DDIM; ++d) {
            float qv = e[d];
            op[(size_t)d * SPAT] = qv;
            float df = qv - zrow[tid * ZPAD + d];
            lsum = fmaf(df, df, lsum);
        }
#pragma unroll
        for (int off = 32; off > 0; off >>= 1)
            lsum += __shfl_down(lsum, off, 64);
        if (tid == 0)
            atomicAdd(loss, lsum * (1.25f / 4194304.0f));
    }
}

extern "C" void kernel_launch(void* const* d_in, const int* in_sizes, int n_in,
                              void* d_out, int out_size, void* d_ws, size_t ws_size,
                              hipStream_t stream) {
    const float* z   = (const float*)d_in[0];   // [2, 64, 32, 32, 32]
    const float* emb = (const float*)d_in[1];   // [1024, 64]
    float* out  = (float*)d_out;                // z_q (4194304) | loss (1) | indices (65536)
    float* loss = out + 4194304;
    float* idxf = out + 4194305;

    float* h_  = (float*)d_ws;                  // [1024]
    float* e2_ = h_ + KDIM;                     // [1024*64]
    __half* eh_ = (__half*)(e2_ + KDIM * DDIM); // [1024*64] halves

    vq_prep_e<<<KDIM / 16, 256, 0, stream>>>(emb, e2_, h_, eh_, loss);
    vq_mfma_kernel<<<NVEC / 64, 256, 0, stream>>>(z, emb, eh_, h_, e2_, out, loss, idxf);
}